// Round 1
// baseline (7439.812 us; speedup 1.0000x reference)
//
#include <hip/hip_runtime.h>
#include <hip/hip_bf16.h>
#include <math.h>

#define NN 10000
#define NE 60000
#define DD 128
#define NL 15
#define LN_EPS 1e-5f

typedef __attribute__((ext_vector_type(8))) short short8;       // 8 bf16 (MFMA A/B frag)
typedef __attribute__((ext_vector_type(4))) float floatx4;      // MFMA C/D frag

__device__ __forceinline__ unsigned short f2bf(float f) {
    unsigned u = __float_as_uint(f);
    u += 0x7fff + ((u >> 16) & 1);   // RNE
    return (unsigned short)(u >> 16);
}
// packed f32x2 -> bf16x2 (v_cvt_pk_bf16_f32 on gfx950), result as one uint
__device__ __forceinline__ unsigned bc2(float a, float b) {
    __hip_bfloat162 t = __float22bfloat162_rn(make_float2(a, b));
    return *(unsigned*)&t;
}
// gelu(y) ~= y * sigmoid(1.5957691*y + 0.0713548*y^3)
__device__ __forceinline__ float gelu_fast(float y) {
    float u = y * y;
    float s2 = y * fmaf(u, 0.07135481283f, 1.59576912161f);
    return y * __builtin_amdgcn_rcpf(1.0f + __expf(-s2));
}

// ---- pack fp32 weights [L][K][N] -> bf16 MFMA B-fragment layout ----
// dst (within layer) = (t*S + s)*512 + l*8 + j ; virtual k = 32s+8(l>>4)+j ; n=16t+(l&15)
// PERM (stage-2 weights, K=256): physical k = ((kv&15)<<4)|(kv>>4)
__device__ __forceinline__ void pack_one(const float* __restrict__ W, unsigned short* __restrict__ P,
                                         int u, int Kk, int Nk, bool perm) {
    int per_layer = Kk * Nk;
    int i = u / per_layer;
    int v0 = u - i * per_layer;
    int S = Kk >> 5;
    int t = v0 / (S * 512);
    int rem = v0 - t * (S * 512);
    int s = rem >> 9;
    int v = rem & 511;
    int l = v >> 3, j = v & 7;
    int kv = (s << 5) + ((l >> 4) << 3) + j;
    int k = perm ? (((kv & 15) << 4) | (kv >> 4)) : kv;
    int n = (t << 4) + (l & 15);
    P[u] = f2bf(W[((size_t)i * Kk + k) * Nk + n]);
}

#define N_EW1 (NL * 384 * 256)
#define N_EW2 (NL * 256 * 128)
#define N_NW1 (NL * 256 * 256)
#define N_NW2 (NL * 256 * 128)

__global__ void pack_all(const float* __restrict__ ew1, const float* __restrict__ ew2,
                         const float* __restrict__ nw1, const float* __restrict__ nw2,
                         unsigned short* __restrict__ P) {
    int tid = blockIdx.x * blockDim.x + threadIdx.x;
    if (tid < N_EW1) { pack_one(ew1, P, tid, 384, 256, false); return; }
    tid -= N_EW1;
    if (tid < N_EW2) { pack_one(ew2, P + N_EW1, tid, 256, 128, true); return; }
    tid -= N_EW2;
    if (tid < N_NW1) { pack_one(nw1, P + N_EW1 + N_EW2, tid, 256, 256, false); return; }
    tid -= N_NW1;
    if (tid < N_NW2) { pack_one(nw2, P + N_EW1 + N_EW2 + N_NW1, tid, 256, 128, true); return; }
}

// ---- degree histogram + reciprocal (CSR no longer needed: agg is atomic-fused) ----
__global__ void hist_kernel(const int* __restrict__ ecol, int* __restrict__ cnt) {
    int e = blockIdx.x * blockDim.x + threadIdx.x;
    if (e < NE) atomicAdd(&cnt[ecol[e]], 1);
}

__global__ void cinv_kernel(const int* __restrict__ cnt, float* __restrict__ cinv) {
    int n = blockIdx.x * blockDim.x + threadIdx.x;
    if (n < NN) {
        int c = cnt[n];
        cinv[n] = 1.0f / (float)(c > 0 ? c : 1);
    }
}

// ---- one-time fp32 -> bf16 shadow conversion for x and edge_attr ----
__global__ void init_shadow(const float* __restrict__ x, const float* __restrict__ ea,
                            unsigned short* __restrict__ xb, unsigned short* __restrict__ eb) {
    int t = blockIdx.x * blockDim.x + threadIdx.x;
    const int NX = NN * DD / 4;
    const int NEA = NE * DD / 4;
    if (t < NX) {
        float4 v = *(const float4*)&x[(size_t)t * 4];
        uint2 p; p.x = bc2(v.x, v.y); p.y = bc2(v.z, v.w);
        *(uint2*)&xb[(size_t)t * 4] = p;
    } else if (t < NX + NEA) {
        size_t u = (size_t)(t - NX);
        float4 v = *(const float4*)&ea[u * 4];
        uint2 p; p.x = bc2(v.x, v.y); p.y = bc2(v.z, v.w);
        *(uint2*)&eb[u * 4] = p;
    }
}

// ---- fused MFMA MLP: 32 rows/block, 4 waves ----
// Gathers read bf16 shadows (half traffic, no convert VALU). Epilogue routes LN2
// output through LDS for a coalesced float4 residual +=, writes the bf16 shadow,
// and (EDGE) atomically accumulates into agg / (NODE) re-zeroes agg for next layer.
template <int K1, int ROWS_TOTAL, bool EDGE>
__global__ __launch_bounds__(256, 4)
void mlp_mfma(const unsigned short* __restrict__ xb16,
              const int* __restrict__ erow, const int* __restrict__ ecol,
              const unsigned short* __restrict__ eab16,   // EDGE gather src (own row)
              float* __restrict__ agg,                    // EDGE: atomic dst; NODE: gather src + zero
              const float* __restrict__ cinv,             // NODE only
              float* __restrict__ target,                 // fp32 residual state (ea / x)
              unsigned short* __restrict__ shadow,        // bf16 shadow of target
              const unsigned short* __restrict__ W1p, const unsigned short* __restrict__ W2p,
              const float* __restrict__ b1, const float* __restrict__ g1, const float* __restrict__ bt1,
              const float* __restrict__ b2, const float* __restrict__ g2, const float* __restrict__ bt2)
{
    constexpr int S1 = K1 / 32;
    constexpr int ROWS = 32;
    constexpr int NIT = K1 / 64;      // gather iterations (6 edge, 4 node)
    __shared__ union {
        unsigned short a1[ROWS * K1];     // gather tile (bf16, XOR-swizzled groups of 8)
        unsigned short h[ROWS * 256];     // stage-1 activations, nibble-swapped col layout
        float of[ROWS * 132];             // LN2 output staging (pad stride 132: 2-way banks)
    } sm;
    __shared__ float red1[ROWS][8];
    __shared__ float red2[ROWS][4];

    const int tid  = threadIdx.x;
    const int lane = tid & 63;
    const int w    = tid >> 6;
    const int q    = lane >> 4;
    const int c15  = lane & 15;
    const int r0   = blockIdx.x * ROWS;

    // ---------------- gather -> a1: thread owns row r=tid>>3, col-group g=tid&7 ----------------
    {
        const int r = tid >> 3;
        const int g = tid & 7;
        const int row_g = r0 + r;
        const bool ok = (ROWS_TOTAL % ROWS == 0) || (row_g < ROWS_TOTAL);
        if constexpr (EDGE) {
            const unsigned short* baseA = &xb16[(size_t)erow[row_g] * DD];
            const unsigned short* baseB = &xb16[(size_t)ecol[row_g] * DD];
            const unsigned short* baseC = &eab16[(size_t)row_g * DD];
            #pragma unroll
            for (int it = 0; it < NIT; ++it) {
                const int gg = g + 8 * it;
                const int p = gg << 3;                  // region uniform per it
                const unsigned short* src = (p < 128) ? (baseA + p)
                                          : (p < 256) ? (baseB + (p - 128))
                                                      : (baseC + (p - 256));
                uint4 v = *(const uint4*)src;
                *(uint4*)&sm.a1[r * K1 + ((gg ^ (r & 7)) << 3)] = v;
            }
        } else {
            const int rsafe = ok ? row_g : 0;
            const unsigned short* baseA = &xb16[(size_t)rsafe * DD];
            const float* baseB = &agg[(size_t)rsafe * DD];
            const float ci = ok ? cinv[rsafe] : 0.f;
            #pragma unroll
            for (int it = 0; it < NIT; ++it) {
                const int gg = g + 8 * it;
                const int p = gg << 3;
                uint4 v;
                if (p < 128) {
                    v = *(const uint4*)(baseA + p);
                    if (!ok) { v.x = 0u; v.y = 0u; v.z = 0u; v.w = 0u; }
                } else {
                    float4 f0 = *(const float4*)(baseB + (p - 128));
                    float4 f1 = *(const float4*)(baseB + (p - 124));
                    v.x = bc2(f0.x * ci, f0.y * ci); v.y = bc2(f0.z * ci, f0.w * ci);
                    v.z = bc2(f1.x * ci, f1.y * ci); v.w = bc2(f1.z * ci, f1.w * ci);
                }
                *(uint4*)&sm.a1[r * K1 + ((gg ^ (r & 7)) << 3)] = v;
            }
        }
    }
    __syncthreads();

    // ---------------- stage 1 MFMA: wave w -> n-tiles 4w..4w+3, m-tiles 0..1 ----------------
    floatx4 acc[2][4];
    #pragma unroll
    for (int mt = 0; mt < 2; ++mt)
        #pragma unroll
        for (int ntl = 0; ntl < 4; ++ntl)
            acc[mt][ntl] = (floatx4){0.f, 0.f, 0.f, 0.f};

    #pragma unroll
    for (int s = 0; s < S1; ++s) {
        short8 af[2];
        #pragma unroll
        for (int mt = 0; mt < 2; ++mt) {
            int row  = (mt << 4) + c15;
            int kgrp = ((s << 2) + q) ^ (row & 7);
            af[mt] = *(const short8*)&sm.a1[row * K1 + (kgrp << 3)];
        }
        #pragma unroll
        for (int ntl = 0; ntl < 4; ++ntl) {
            const short8 bf = *(const short8*)&W1p[((((((w << 2) + ntl) * S1) + s) << 6) + lane) << 3];
            #pragma unroll
            for (int mt = 0; mt < 2; ++mt)
                acc[mt][ntl] = __builtin_amdgcn_mfma_f32_16x16x32_bf16(af[mt], bf, acc[mt][ntl], 0, 0, 0);
        }
    }

    // bias + in-register LN1 partial stats
    float b1c[4], g1c[4], t1c[4];
    #pragma unroll
    for (int ntl = 0; ntl < 4; ++ntl) {
        int col = (((w << 2) + ntl) << 4) + c15;
        b1c[ntl] = b1[col]; g1c[ntl] = g1[col]; t1c[ntl] = bt1[col];
    }
    #pragma unroll
    for (int mt = 0; mt < 2; ++mt)
        #pragma unroll
        for (int r = 0; r < 4; ++r) {
            float p = 0.f, sq = 0.f;
            #pragma unroll
            for (int ntl = 0; ntl < 4; ++ntl) {
                float v = acc[mt][ntl][r] + b1c[ntl];
                acc[mt][ntl][r] = v;
                p += v; sq += v * v;
            }
            p += __shfl_xor(p, 1);  sq += __shfl_xor(sq, 1);
            p += __shfl_xor(p, 2);  sq += __shfl_xor(sq, 2);
            p += __shfl_xor(p, 4);  sq += __shfl_xor(sq, 4);
            p += __shfl_xor(p, 8);  sq += __shfl_xor(sq, 8);
            if (c15 == 0) {
                int row = (mt << 4) + (q << 2) + r;
                red1[row][(w << 1) + 0] = p;
                red1[row][(w << 1) + 1] = sq;
            }
        }
    __syncthreads();   // red1 visible; all waves done with a1 -> h writes safe

    // ---- apply LN1 + GELU in reg, write H' once as b64 (nibble-swapped cols) ----
    #pragma unroll
    for (int mt = 0; mt < 2; ++mt)
        #pragma unroll
        for (int r = 0; r < 4; ++r) {
            int row = (mt << 4) + (q << 2) + r;
            const float4 p0 = *(const float4*)&red1[row][0];
            const float4 p1 = *(const float4*)&red1[row][4];
            float p  = p0.x + p0.z + p1.x + p1.z;
            float sq = p0.y + p0.w + p1.y + p1.w;
            float mu = p * (1.0f / 256.0f);
            float rs = rsqrtf(sq * (1.0f / 256.0f) - mu * mu + LN_EPS);
            float y0 = gelu_fast((acc[mt][0][r] - mu) * rs * g1c[0] + t1c[0]);
            float y1 = gelu_fast((acc[mt][1][r] - mu) * rs * g1c[1] + t1c[1]);
            float y2 = gelu_fast((acc[mt][2][r] - mu) * rs * g1c[2] + t1c[2]);
            float y3 = gelu_fast((acc[mt][3][r] - mu) * rs * g1c[3] + t1c[3]);
            uint2 hp;
            hp.x = bc2(y0, y1);
            hp.y = bc2(y2, y3);
            int gg = (c15 << 1) + (w >> 1);
            int addr = row * 256 + (((gg ^ (row & 7)) << 3) | ((w & 1) << 2));
            *(uint2*)&sm.h[addr] = hp;
        }
    __syncthreads();

    // ---------------- stage 2: wave w -> m-tile (w&1), n-tiles (w>>1)*4.. ----------------
    floatx4 acc2[4];
    #pragma unroll
    for (int j = 0; j < 4; ++j) acc2[j] = (floatx4){0.f, 0.f, 0.f, 0.f};

    const int mrow = ((w & 1) << 4) + c15;
    const int nh   = w >> 1;
    #pragma unroll
    for (int s = 0; s < 8; ++s) {
        int kgrp = ((s << 2) + q) ^ (mrow & 7);
        const short8 a = *(const short8*)&sm.h[mrow * 256 + (kgrp << 3)];
        #pragma unroll
        for (int j = 0; j < 4; ++j) {
            int nt = (nh << 2) + j;
            const short8 b = *(const short8*)&W2p[((((nt << 3) + s) << 6) + lane) << 3];
            acc2[j] = __builtin_amdgcn_mfma_f32_16x16x32_bf16(a, b, acc2[j], 0, 0, 0);
        }
    }

    float b2c[4], g2c[4], t2c[4];
    #pragma unroll
    for (int j = 0; j < 4; ++j) {
        int col = (((nh << 2) + j) << 4) + c15;
        b2c[j] = b2[col]; g2c[j] = g2[col]; t2c[j] = bt2[col];
    }
    #pragma unroll
    for (int r = 0; r < 4; ++r) {
        float p = 0.f, sq = 0.f;
        #pragma unroll
        for (int j = 0; j < 4; ++j) {
            float v = acc2[j][r] + b2c[j];
            acc2[j][r] = v;
            p += v; sq += v * v;
        }
        p += __shfl_xor(p, 1);  sq += __shfl_xor(sq, 1);
        p += __shfl_xor(p, 2);  sq += __shfl_xor(sq, 2);
        p += __shfl_xor(p, 4);  sq += __shfl_xor(sq, 4);
        p += __shfl_xor(p, 8);  sq += __shfl_xor(sq, 8);
        if (c15 == 0) {
            int row = ((w & 1) << 4) + (q << 2) + r;
            red2[row][(nh << 1) + 0] = p;
            red2[row][(nh << 1) + 1] = sq;
        }
    }
    __syncthreads();   // red2 visible; all stage-2 reads of sm.h done -> sm.of writes safe

    // ---------------- epilogue, scattered phase: LN2 -> LDS ----------------
    #pragma unroll
    for (int r = 0; r < 4; ++r) {
        int row = ((w & 1) << 4) + (q << 2) + r;
        const float4 pp = *(const float4*)&red2[row][0];
        float p  = pp.x + pp.z;
        float sq = pp.y + pp.w;
        float mu = p * (1.0f / 128.0f);
        float rs = rsqrtf(sq * (1.0f / 128.0f) - mu * mu + LN_EPS);
        #pragma unroll
        for (int j = 0; j < 4; ++j) {
            int col = (((nh << 2) + j) << 4) + c15;
            sm.of[row * 132 + col] = (acc2[j][r] - mu) * rs * g2c[j] + t2c[j];
        }
    }
    __syncthreads();

    // ---------------- epilogue, linear phase: residual += , bf16 shadow, agg ----------------
    {
        const int r  = tid >> 3;
        const int c0 = (tid & 7) << 4;
        const int rowg = r0 + r;
        if (ROWS_TOTAL % ROWS == 0 || rowg < ROWS_TOTAL) {
            const float* ofp = &sm.of[r * 132 + c0];
            float4 o0 = *(const float4*)(ofp + 0);
            float4 o1 = *(const float4*)(ofp + 4);
            float4 o2 = *(const float4*)(ofp + 8);
            float4 o3 = *(const float4*)(ofp + 12);
            float* tp = &target[(size_t)rowg * DD + c0];
            float4 t0 = *(const float4*)(tp + 0);
            float4 t1 = *(const float4*)(tp + 4);
            float4 t2 = *(const float4*)(tp + 8);
            float4 t3 = *(const float4*)(tp + 12);
            t0.x += o0.x; t0.y += o0.y; t0.z += o0.z; t0.w += o0.w;
            t1.x += o1.x; t1.y += o1.y; t1.z += o1.z; t1.w += o1.w;
            t2.x += o2.x; t2.y += o2.y; t2.z += o2.z; t2.w += o2.w;
            t3.x += o3.x; t3.y += o3.y; t3.z += o3.z; t3.w += o3.w;
            *(float4*)(tp + 0)  = t0;
            *(float4*)(tp + 4)  = t1;
            *(float4*)(tp + 8)  = t2;
            *(float4*)(tp + 12) = t3;
            uint4 s0, s1;
            s0.x = bc2(t0.x, t0.y); s0.y = bc2(t0.z, t0.w);
            s0.z = bc2(t1.x, t1.y); s0.w = bc2(t1.z, t1.w);
            s1.x = bc2(t2.x, t2.y); s1.y = bc2(t2.z, t2.w);
            s1.z = bc2(t3.x, t3.y); s1.w = bc2(t3.z, t3.w);
            *(uint4*)&shadow[(size_t)rowg * DD + c0]     = s0;
            *(uint4*)&shadow[(size_t)rowg * DD + c0 + 8] = s1;
            if constexpr (EDGE) {
                float* ag = &agg[(size_t)ecol[rowg] * DD + c0];
                atomicAdd(ag + 0,  t0.x); atomicAdd(ag + 1,  t0.y);
                atomicAdd(ag + 2,  t0.z); atomicAdd(ag + 3,  t0.w);
                atomicAdd(ag + 4,  t1.x); atomicAdd(ag + 5,  t1.y);
                atomicAdd(ag + 6,  t1.z); atomicAdd(ag + 7,  t1.w);
                atomicAdd(ag + 8,  t2.x); atomicAdd(ag + 9,  t2.y);
                atomicAdd(ag + 10, t2.z); atomicAdd(ag + 11, t2.w);
                atomicAdd(ag + 12, t3.x); atomicAdd(ag + 13, t3.y);
                atomicAdd(ag + 14, t3.z); atomicAdd(ag + 15, t3.w);
            } else {
                // consumed our agg rows in the gather; zero them for the next layer's atomics
                float4 z; z.x = 0.f; z.y = 0.f; z.z = 0.f; z.w = 0.f;
                float* ap = &agg[(size_t)rowg * DD + c0];
                *(float4*)(ap + 0)  = z;
                *(float4*)(ap + 4)  = z;
                *(float4*)(ap + 8)  = z;
                *(float4*)(ap + 12) = z;
            }
        }
    }
}

extern "C" void kernel_launch(void* const* d_in, const int* in_sizes, int n_in,
                              void* d_out, int out_size, void* d_ws, size_t ws_size,
                              hipStream_t stream) {
    const float* x_in  = (const float*)d_in[0];
    const int*   ei    = (const int*)  d_in[1];
    const float* ea_in = (const float*)d_in[2];
    const float* ew1 = (const float*)d_in[3];
    const float* eb1 = (const float*)d_in[4];
    const float* eg1 = (const float*)d_in[5];
    const float* ebt1= (const float*)d_in[6];
    const float* ew2 = (const float*)d_in[7];
    const float* eb2 = (const float*)d_in[8];
    const float* eg2 = (const float*)d_in[9];
    const float* ebt2= (const float*)d_in[10];
    const float* nw1 = (const float*)d_in[11];
    const float* nb1 = (const float*)d_in[12];
    const float* ng1 = (const float*)d_in[13];
    const float* nbt1= (const float*)d_in[14];
    const float* nw2 = (const float*)d_in[15];
    const float* nb2 = (const float*)d_in[16];
    const float* ng2 = (const float*)d_in[17];
    const float* nbt2= (const float*)d_in[18];

    const int* erow = ei;
    const int* ecol = ei + NE;

    float* xbuf  = (float*)d_out;            // [NN, DD] fp32 residual state
    float* eabuf = (float*)d_out + NN * DD;  // [NE, DD] fp32 residual state

    // workspace layout
    unsigned short* ew1p  = (unsigned short*)d_ws;
    unsigned short* ew2p  = ew1p + N_EW1;
    unsigned short* nw1p  = ew2p + N_EW2;
    unsigned short* nw2p  = nw1p + N_NW1;
    unsigned short* xb16  = nw2p + N_NW2;          // [NN, DD] bf16 shadow of x
    unsigned short* eab16 = xb16 + (size_t)NN * DD; // [NE, DD] bf16 shadow of edge_attr
    int*   cnt  = (int*)(eab16 + (size_t)NE * DD);
    float* cinv = (float*)(cnt + NN);
    float* agg  = cinv + NN;                        // [NN, DD] fp32 atomic accumulator

    hipMemcpyAsync(xbuf,  x_in,  (size_t)NN * DD * sizeof(float), hipMemcpyDeviceToDevice, stream);
    hipMemcpyAsync(eabuf, ea_in, (size_t)NE * DD * sizeof(float), hipMemcpyDeviceToDevice, stream);

    // degree counts + reciprocal
    hipMemsetAsync(cnt, 0, NN * sizeof(int), stream);
    hipMemsetAsync(agg, 0, (size_t)NN * DD * sizeof(float), stream);
    hist_kernel<<<(NE + 255) / 256, 256, 0, stream>>>(ecol, cnt);
    cinv_kernel<<<(NN + 255) / 256, 256, 0, stream>>>(cnt, cinv);

    // bf16 shadows of the initial state
    {
        int ntot = (NN * DD + NE * DD) / 4;
        init_shadow<<<(ntot + 255) / 256, 256, 0, stream>>>(x_in, ea_in, xb16, eab16);
    }

    // weight packing (stage-2 weights get the k-permutation)
    {
        int ntot = N_EW1 + N_EW2 + N_NW1 + N_NW2;
        pack_all<<<(ntot + 255) / 256, 256, 0, stream>>>(ew1, ew2, nw1, nw2, ew1p);
    }

    for (int i = 0; i < NL; ++i) {
        mlp_mfma<384, NE, true><<<NE / 32, 256, 0, stream>>>(
            xb16, erow, ecol, eab16, agg, nullptr, eabuf, eab16,
            ew1p + (size_t)i * 384 * 256, ew2p + (size_t)i * 256 * 128,
            eb1 + (size_t)i * 256, eg1 + (size_t)i * 256, ebt1 + (size_t)i * 256,
            eb2 + (size_t)i * 128, eg2 + (size_t)i * 128, ebt2 + (size_t)i * 128);
        mlp_mfma<256, NN, false><<<(NN + 31) / 32, 256, 0, stream>>>(
            xb16, nullptr, nullptr, nullptr, agg, cinv, xbuf, xb16,
            nw1p + (size_t)i * 256 * 256, nw2p + (size_t)i * 256 * 128,
            nb1 + (size_t)i * 256, ng1 + (size_t)i * 256, nbt1 + (size_t)i * 256,
            nb2 + (size_t)i * 128, ng2 + (size_t)i * 128, nbt2 + (size_t)i * 128);
    }
}

// Round 3
// 1438.577 us; speedup vs baseline: 5.1716x; 5.1716x over previous
//
#include <hip/hip_runtime.h>
#include <hip/hip_bf16.h>
#include <math.h>

#define NN 10000
#define NE 60000
#define DD 128
#define NL 15
#define LN_EPS 1e-5f

typedef __attribute__((ext_vector_type(8))) short short8;       // 8 bf16 (MFMA A/B frag)
typedef __attribute__((ext_vector_type(4))) float floatx4;      // MFMA C/D frag

__device__ __forceinline__ unsigned short f2bf(float f) {
    unsigned u = __float_as_uint(f);
    u += 0x7fff + ((u >> 16) & 1);   // RNE
    return (unsigned short)(u >> 16);
}
// packed f32x2 -> bf16x2 (v_cvt_pk_bf16_f32 on gfx950), result as one uint
__device__ __forceinline__ unsigned bc2(float a, float b) {
    __hip_bfloat162 t = __float22bfloat162_rn(make_float2(a, b));
    return *(unsigned*)&t;
}
// gelu(y) ~= y * sigmoid(1.5957691*y + 0.0713548*y^3)
__device__ __forceinline__ float gelu_fast(float y) {
    float u = y * y;
    float s2 = y * fmaf(u, 0.07135481283f, 1.59576912161f);
    return y * __builtin_amdgcn_rcpf(1.0f + __expf(-s2));
}

// ---- pack fp32 weights [L][K][N] -> bf16 MFMA B-fragment layout ----
// dst (within layer) = (t*S + s)*512 + l*8 + j ; virtual k = 32s+8(l>>4)+j ; n=16t+(l&15)
// PERM (stage-2 weights, K=256): physical k = ((kv&15)<<4)|(kv>>4)
__device__ __forceinline__ void pack_one(const float* __restrict__ W, unsigned short* __restrict__ P,
                                         int u, int Kk, int Nk, bool perm) {
    int per_layer = Kk * Nk;
    int i = u / per_layer;
    int v0 = u - i * per_layer;
    int S = Kk >> 5;
    int t = v0 / (S * 512);
    int rem = v0 - t * (S * 512);
    int s = rem >> 9;
    int v = rem & 511;
    int l = v >> 3, j = v & 7;
    int kv = (s << 5) + ((l >> 4) << 3) + j;
    int k = perm ? (((kv & 15) << 4) | (kv >> 4)) : kv;
    int n = (t << 4) + (l & 15);
    P[u] = f2bf(W[((size_t)i * Kk + k) * Nk + n]);
}

#define N_EW1 (NL * 384 * 256)
#define N_EW2 (NL * 256 * 128)
#define N_NW1 (NL * 256 * 256)
#define N_NW2 (NL * 256 * 128)

__global__ void pack_all(const float* __restrict__ ew1, const float* __restrict__ ew2,
                         const float* __restrict__ nw1, const float* __restrict__ nw2,
                         unsigned short* __restrict__ P) {
    int tid = blockIdx.x * blockDim.x + threadIdx.x;
    if (tid < N_EW1) { pack_one(ew1, P, tid, 384, 256, false); return; }
    tid -= N_EW1;
    if (tid < N_EW2) { pack_one(ew2, P + N_EW1, tid, 256, 128, true); return; }
    tid -= N_EW2;
    if (tid < N_NW1) { pack_one(nw1, P + N_EW1 + N_EW2, tid, 256, 256, false); return; }
    tid -= N_NW1;
    if (tid < N_NW2) { pack_one(nw2, P + N_EW1 + N_EW2 + N_NW1, tid, 256, 128, true); return; }
}

// ---- CSR build (once per launch) ----
__global__ void hist_kernel(const int* __restrict__ ecol, int* __restrict__ cnt) {
    int e = blockIdx.x * blockDim.x + threadIdx.x;
    if (e < NE) atomicAdd(&cnt[ecol[e]], 1);
}

__global__ void scan_kernel(const int* __restrict__ cnt, int* __restrict__ starts,
                            int* __restrict__ cursor, float* __restrict__ cinv) {
    __shared__ int part[256];
    int t = threadIdx.x;
    const int chunk = (NN + 255) / 256;
    int lo = t * chunk;
    int hi = lo + chunk; if (hi > NN) hi = NN;
    int s = 0;
    for (int n = lo; n < hi; ++n) s += cnt[n];
    part[t] = s;
    __syncthreads();
    for (int off = 1; off < 256; off <<= 1) {
        int v = (t >= off) ? part[t - off] : 0;
        __syncthreads();
        part[t] += v;
        __syncthreads();
    }
    int base = part[t] - s;
    for (int n = lo; n < hi; ++n) {
        int c = cnt[n];
        starts[n] = base; cursor[n] = base;
        cinv[n] = 1.0f / (float)(c > 0 ? c : 1);
        base += c;
    }
}

__global__ void fill_kernel(const int* __restrict__ ecol, int* __restrict__ cursor,
                            int* __restrict__ eidx) {
    int e = blockIdx.x * blockDim.x + threadIdx.x;
    if (e < NE) {
        int slot = atomicAdd(&cursor[ecol[e]], 1);
        eidx[slot] = e;
    }
}

// ---- aggregation: one wave per node, lane covers 2 cols (coalesced 512B/edge) ----
// Output = mean (cinv applied HERE; node gather must NOT rescale).
__global__ __launch_bounds__(256)
void agg_kernel(const float* __restrict__ ea, const int* __restrict__ starts,
                const int* __restrict__ cnt, const float* __restrict__ cinv,
                const int* __restrict__ eidx, float* __restrict__ agg) {
    int n = blockIdx.x * 4 + (threadIdx.x >> 6);
    if (n >= NN) return;
    int lane = threadIdx.x & 63;
    int st = starts[n], de = cnt[n];
    float sx = 0.f, sy = 0.f;
    for (int i = 0; i < de; ++i) {
        int e = eidx[st + i];
        const float2 v = *(const float2*)&ea[(size_t)e * DD + lane * 2];
        sx += v.x; sy += v.y;
    }
    float ci = cinv[n];
    float2 o; o.x = sx * ci; o.y = sy * ci;
    *(float2*)&agg[(size_t)n * DD + lane * 2] = o;
}

// ---- one-time fp32 -> bf16 shadow conversion for x and edge_attr ----
__global__ void init_shadow(const float* __restrict__ x, const float* __restrict__ ea,
                            unsigned short* __restrict__ xb, unsigned short* __restrict__ eb) {
    int t = blockIdx.x * blockDim.x + threadIdx.x;
    const int NX = NN * DD / 4;
    const int NEA = NE * DD / 4;
    if (t < NX) {
        float4 v = *(const float4*)&x[(size_t)t * 4];
        uint2 p; p.x = bc2(v.x, v.y); p.y = bc2(v.z, v.w);
        *(uint2*)&xb[(size_t)t * 4] = p;
    } else if (t < NX + NEA) {
        size_t u = (size_t)(t - NX);
        float4 v = *(const float4*)&ea[u * 4];
        uint2 p; p.x = bc2(v.x, v.y); p.y = bc2(v.z, v.w);
        *(uint2*)&eb[u * 4] = p;
    }
}

// ---- fused MFMA MLP: 32 rows/block, 4 waves ----
// Gathers read bf16 shadows (half traffic, no convert VALU). Epilogue routes LN2
// output through LDS for a coalesced float4 residual += plus bf16 shadow write.
// Aggregation is a separate CSR pass (fused atomics measured 10x worse: 285MB HBM RMW).
template <int K1, int ROWS_TOTAL, bool EDGE>
__global__ __launch_bounds__(256, 4)
void mlp_mfma(const unsigned short* __restrict__ xb16,
              const int* __restrict__ erow, const int* __restrict__ ecol,
              const unsigned short* __restrict__ eab16,   // EDGE gather src (own row)
              const float* __restrict__ agg,              // NODE gather src (dense fp32 MEAN)
              float* __restrict__ target,                 // fp32 residual state (ea / x)
              unsigned short* __restrict__ shadow,        // bf16 shadow of target
              const unsigned short* __restrict__ W1p, const unsigned short* __restrict__ W2p,
              const float* __restrict__ b1, const float* __restrict__ g1, const float* __restrict__ bt1,
              const float* __restrict__ b2, const float* __restrict__ g2, const float* __restrict__ bt2)
{
    constexpr int S1 = K1 / 32;
    constexpr int ROWS = 32;
    constexpr int NIT = K1 / 64;      // gather iterations (6 edge, 4 node)
    __shared__ union {
        unsigned short a1[ROWS * K1];     // gather tile (bf16, XOR-swizzled groups of 8)
        unsigned short h[ROWS * 256];     // stage-1 activations, nibble-swapped col layout
        float of[ROWS * 132];             // LN2 output staging (pad stride 132: 2-way banks)
    } sm;
    __shared__ float red1[ROWS][8];
    __shared__ float red2[ROWS][4];

    const int tid  = threadIdx.x;
    const int lane = tid & 63;
    const int w    = tid >> 6;
    const int q    = lane >> 4;
    const int c15  = lane & 15;
    const int r0   = blockIdx.x * ROWS;

    // ---------------- gather -> a1: thread owns row r=tid>>3, col-group g=tid&7 ----------------
    {
        const int r = tid >> 3;
        const int g = tid & 7;
        const int row_g = r0 + r;
        const bool ok = (ROWS_TOTAL % ROWS == 0) || (row_g < ROWS_TOTAL);
        if constexpr (EDGE) {
            const unsigned short* baseA = &xb16[(size_t)erow[row_g] * DD];
            const unsigned short* baseB = &xb16[(size_t)ecol[row_g] * DD];
            const unsigned short* baseC = &eab16[(size_t)row_g * DD];
            #pragma unroll
            for (int it = 0; it < NIT; ++it) {
                const int gg = g + 8 * it;
                const int p = gg << 3;                  // region uniform per it
                const unsigned short* src = (p < 128) ? (baseA + p)
                                          : (p < 256) ? (baseB + (p - 128))
                                                      : (baseC + (p - 256));
                uint4 v = *(const uint4*)src;
                *(uint4*)&sm.a1[r * K1 + ((gg ^ (r & 7)) << 3)] = v;
            }
        } else {
            const int rsafe = ok ? row_g : 0;
            const unsigned short* baseA = &xb16[(size_t)rsafe * DD];
            const float* baseB = &agg[(size_t)rsafe * DD];
            #pragma unroll
            for (int it = 0; it < NIT; ++it) {
                const int gg = g + 8 * it;
                const int p = gg << 3;
                uint4 v;
                if (p < 128) {
                    v = *(const uint4*)(baseA + p);
                    if (!ok) { v.x = 0u; v.y = 0u; v.z = 0u; v.w = 0u; }
                } else {
                    float4 f0 = *(const float4*)(baseB + (p - 128));
                    float4 f1 = *(const float4*)(baseB + (p - 124));
                    v.x = bc2(f0.x, f0.y); v.y = bc2(f0.z, f0.w);
                    v.z = bc2(f1.x, f1.y); v.w = bc2(f1.z, f1.w);
                }
                *(uint4*)&sm.a1[r * K1 + ((gg ^ (r & 7)) << 3)] = v;
            }
        }
    }
    __syncthreads();

    // ---------------- stage 1 MFMA: wave w -> n-tiles 4w..4w+3, m-tiles 0..1 ----------------
    floatx4 acc[2][4];
    #pragma unroll
    for (int mt = 0; mt < 2; ++mt)
        #pragma unroll
        for (int ntl = 0; ntl < 4; ++ntl)
            acc[mt][ntl] = (floatx4){0.f, 0.f, 0.f, 0.f};

    #pragma unroll
    for (int s = 0; s < S1; ++s) {
        short8 af[2];
        #pragma unroll
        for (int mt = 0; mt < 2; ++mt) {
            int row  = (mt << 4) + c15;
            int kgrp = ((s << 2) + q) ^ (row & 7);
            af[mt] = *(const short8*)&sm.a1[row * K1 + (kgrp << 3)];
        }
        #pragma unroll
        for (int ntl = 0; ntl < 4; ++ntl) {
            const short8 bf = *(const short8*)&W1p[((((((w << 2) + ntl) * S1) + s) << 6) + lane) << 3];
            #pragma unroll
            for (int mt = 0; mt < 2; ++mt)
                acc[mt][ntl] = __builtin_amdgcn_mfma_f32_16x16x32_bf16(af[mt], bf, acc[mt][ntl], 0, 0, 0);
        }
    }

    // bias + in-register LN1 partial stats
    float b1c[4], g1c[4], t1c[4];
    #pragma unroll
    for (int ntl = 0; ntl < 4; ++ntl) {
        int col = (((w << 2) + ntl) << 4) + c15;
        b1c[ntl] = b1[col]; g1c[ntl] = g1[col]; t1c[ntl] = bt1[col];
    }
    #pragma unroll
    for (int mt = 0; mt < 2; ++mt)
        #pragma unroll
        for (int r = 0; r < 4; ++r) {
            float p = 0.f, sq = 0.f;
            #pragma unroll
            for (int ntl = 0; ntl < 4; ++ntl) {
                float v = acc[mt][ntl][r] + b1c[ntl];
                acc[mt][ntl][r] = v;
                p += v; sq += v * v;
            }
            p += __shfl_xor(p, 1);  sq += __shfl_xor(sq, 1);
            p += __shfl_xor(p, 2);  sq += __shfl_xor(sq, 2);
            p += __shfl_xor(p, 4);  sq += __shfl_xor(sq, 4);
            p += __shfl_xor(p, 8);  sq += __shfl_xor(sq, 8);
            if (c15 == 0) {
                int row = (mt << 4) + (q << 2) + r;
                red1[row][(w << 1) + 0] = p;
                red1[row][(w << 1) + 1] = sq;
            }
        }
    __syncthreads();   // red1 visible; all waves done with a1 -> h writes safe

    // ---- apply LN1 + GELU in reg, write H' once as b64 (nibble-swapped cols) ----
    #pragma unroll
    for (int mt = 0; mt < 2; ++mt)
        #pragma unroll
        for (int r = 0; r < 4; ++r) {
            int row = (mt << 4) + (q << 2) + r;
            const float4 p0 = *(const float4*)&red1[row][0];
            const float4 p1 = *(const float4*)&red1[row][4];
            float p  = p0.x + p0.z + p1.x + p1.z;
            float sq = p0.y + p0.w + p1.y + p1.w;
            float mu = p * (1.0f / 256.0f);
            float rs = rsqrtf(sq * (1.0f / 256.0f) - mu * mu + LN_EPS);
            float y0 = gelu_fast((acc[mt][0][r] - mu) * rs * g1c[0] + t1c[0]);
            float y1 = gelu_fast((acc[mt][1][r] - mu) * rs * g1c[1] + t1c[1]);
            float y2 = gelu_fast((acc[mt][2][r] - mu) * rs * g1c[2] + t1c[2]);
            float y3 = gelu_fast((acc[mt][3][r] - mu) * rs * g1c[3] + t1c[3]);
            uint2 hp;
            hp.x = bc2(y0, y1);
            hp.y = bc2(y2, y3);
            int gg = (c15 << 1) + (w >> 1);
            int addr = row * 256 + (((gg ^ (row & 7)) << 3) | ((w & 1) << 2));
            *(uint2*)&sm.h[addr] = hp;
        }
    __syncthreads();

    // ---------------- stage 2: wave w -> m-tile (w&1), n-tiles (w>>1)*4.. ----------------
    floatx4 acc2[4];
    #pragma unroll
    for (int j = 0; j < 4; ++j) acc2[j] = (floatx4){0.f, 0.f, 0.f, 0.f};

    const int mrow = ((w & 1) << 4) + c15;
    const int nh   = w >> 1;
    #pragma unroll
    for (int s = 0; s < 8; ++s) {
        int kgrp = ((s << 2) + q) ^ (mrow & 7);
        const short8 a = *(const short8*)&sm.h[mrow * 256 + (kgrp << 3)];
        #pragma unroll
        for (int j = 0; j < 4; ++j) {
            int nt = (nh << 2) + j;
            const short8 b = *(const short8*)&W2p[((((nt << 3) + s) << 6) + lane) << 3];
            acc2[j] = __builtin_amdgcn_mfma_f32_16x16x32_bf16(a, b, acc2[j], 0, 0, 0);
        }
    }

    float b2c[4], g2c[4], t2c[4];
    #pragma unroll
    for (int j = 0; j < 4; ++j) {
        int col = (((nh << 2) + j) << 4) + c15;
        b2c[j] = b2[col]; g2c[j] = g2[col]; t2c[j] = bt2[col];
    }
    #pragma unroll
    for (int r = 0; r < 4; ++r) {
        float p = 0.f, sq = 0.f;
        #pragma unroll
        for (int j = 0; j < 4; ++j) {
            float v = acc2[j][r] + b2c[j];
            acc2[j][r] = v;
            p += v; sq += v * v;
        }
        p += __shfl_xor(p, 1);  sq += __shfl_xor(sq, 1);
        p += __shfl_xor(p, 2);  sq += __shfl_xor(sq, 2);
        p += __shfl_xor(p, 4);  sq += __shfl_xor(sq, 4);
        p += __shfl_xor(p, 8);  sq += __shfl_xor(sq, 8);
        if (c15 == 0) {
            int row = ((w & 1) << 4) + (q << 2) + r;
            red2[row][(nh << 1) + 0] = p;
            red2[row][(nh << 1) + 1] = sq;
        }
    }
    __syncthreads();   // red2 visible; all stage-2 reads of sm.h done -> sm.of writes safe

    // ---------------- epilogue, scattered phase: LN2 -> LDS ----------------
    #pragma unroll
    for (int r = 0; r < 4; ++r) {
        int row = ((w & 1) << 4) + (q << 2) + r;
        const float4 pp = *(const float4*)&red2[row][0];
        float p  = pp.x + pp.z;
        float sq = pp.y + pp.w;
        float mu = p * (1.0f / 128.0f);
        float rs = rsqrtf(sq * (1.0f / 128.0f) - mu * mu + LN_EPS);
        #pragma unroll
        for (int j = 0; j < 4; ++j) {
            int col = (((nh << 2) + j) << 4) + c15;
            sm.of[row * 132 + col] = (acc2[j][r] - mu) * rs * g2c[j] + t2c[j];
        }
    }
    __syncthreads();

    // ---------------- epilogue, linear phase: residual += , bf16 shadow ----------------
    {
        const int r  = tid >> 3;
        const int c0 = (tid & 7) << 4;
        const int rowg = r0 + r;
        if (ROWS_TOTAL % ROWS == 0 || rowg < ROWS_TOTAL) {
            const float* ofp = &sm.of[r * 132 + c0];
            float4 o0 = *(const float4*)(ofp + 0);
            float4 o1 = *(const float4*)(ofp + 4);
            float4 o2 = *(const float4*)(ofp + 8);
            float4 o3 = *(const float4*)(ofp + 12);
            float* tp = &target[(size_t)rowg * DD + c0];
            float4 t0 = *(const float4*)(tp + 0);
            float4 t1 = *(const float4*)(tp + 4);
            float4 t2 = *(const float4*)(tp + 8);
            float4 t3 = *(const float4*)(tp + 12);
            t0.x += o0.x; t0.y += o0.y; t0.z += o0.z; t0.w += o0.w;
            t1.x += o1.x; t1.y += o1.y; t1.z += o1.z; t1.w += o1.w;
            t2.x += o2.x; t2.y += o2.y; t2.z += o2.z; t2.w += o2.w;
            t3.x += o3.x; t3.y += o3.y; t3.z += o3.z; t3.w += o3.w;
            *(float4*)(tp + 0)  = t0;
            *(float4*)(tp + 4)  = t1;
            *(float4*)(tp + 8)  = t2;
            *(float4*)(tp + 12) = t3;
            uint4 s0, s1;
            s0.x = bc2(t0.x, t0.y); s0.y = bc2(t0.z, t0.w);
            s0.z = bc2(t1.x, t1.y); s0.w = bc2(t1.z, t1.w);
            s1.x = bc2(t2.x, t2.y); s1.y = bc2(t2.z, t2.w);
            s1.z = bc2(t3.x, t3.y); s1.w = bc2(t3.z, t3.w);
            *(uint4*)&shadow[(size_t)rowg * DD + c0]     = s0;
            *(uint4*)&shadow[(size_t)rowg * DD + c0 + 8] = s1;
        }
    }
}

extern "C" void kernel_launch(void* const* d_in, const int* in_sizes, int n_in,
                              void* d_out, int out_size, void* d_ws, size_t ws_size,
                              hipStream_t stream) {
    const float* x_in  = (const float*)d_in[0];
    const int*   ei    = (const int*)  d_in[1];
    const float* ea_in = (const float*)d_in[2];
    const float* ew1 = (const float*)d_in[3];
    const float* eb1 = (const float*)d_in[4];
    const float* eg1 = (const float*)d_in[5];
    const float* ebt1= (const float*)d_in[6];
    const float* ew2 = (const float*)d_in[7];
    const float* eb2 = (const float*)d_in[8];
    const float* eg2 = (const float*)d_in[9];
    const float* ebt2= (const float*)d_in[10];
    const float* nw1 = (const float*)d_in[11];
    const float* nb1 = (const float*)d_in[12];
    const float* ng1 = (const float*)d_in[13];
    const float* nbt1= (const float*)d_in[14];
    const float* nw2 = (const float*)d_in[15];
    const float* nb2 = (const float*)d_in[16];
    const float* ng2 = (const float*)d_in[17];
    const float* nbt2= (const float*)d_in[18];

    const int* erow = ei;
    const int* ecol = ei + NE;

    float* xbuf  = (float*)d_out;            // [NN, DD] fp32 residual state
    float* eabuf = (float*)d_out + NN * DD;  // [NE, DD] fp32 residual state

    // workspace layout
    unsigned short* ew1p  = (unsigned short*)d_ws;
    unsigned short* ew2p  = ew1p + N_EW1;
    unsigned short* nw1p  = ew2p + N_EW2;
    unsigned short* nw2p  = nw1p + N_NW1;
    unsigned short* xb16  = nw2p + N_NW2;           // [NN, DD] bf16 shadow of x
    unsigned short* eab16 = xb16 + (size_t)NN * DD; // [NE, DD] bf16 shadow of edge_attr
    int*   cnt    = (int*)(eab16 + (size_t)NE * DD);
    int*   starts = cnt + NN;
    int*   cursor = starts + NN;
    int*   eidx   = cursor + NN;
    float* cinv   = (float*)(eidx + NE);
    float* agg    = cinv + NN;                      // [NN, DD] fp32 (mean)

    hipMemcpyAsync(xbuf,  x_in,  (size_t)NN * DD * sizeof(float), hipMemcpyDeviceToDevice, stream);
    hipMemcpyAsync(eabuf, ea_in, (size_t)NE * DD * sizeof(float), hipMemcpyDeviceToDevice, stream);

    // CSR build
    hipMemsetAsync(cnt, 0, NN * sizeof(int), stream);
    hist_kernel<<<(NE + 255) / 256, 256, 0, stream>>>(ecol, cnt);
    scan_kernel<<<1, 256, 0, stream>>>(cnt, starts, cursor, cinv);
    fill_kernel<<<(NE + 255) / 256, 256, 0, stream>>>(ecol, cursor, eidx);

    // bf16 shadows of the initial state
    {
        int ntot = (NN * DD + NE * DD) / 4;
        init_shadow<<<(ntot + 255) / 256, 256, 0, stream>>>(x_in, ea_in, xb16, eab16);
    }

    // weight packing (stage-2 weights get the k-permutation)
    {
        int ntot = N_EW1 + N_EW2 + N_NW1 + N_NW2;
        pack_all<<<(ntot + 255) / 256, 256, 0, stream>>>(ew1, ew2, nw1, nw2, ew1p);
    }

    for (int i = 0; i < NL; ++i) {
        mlp_mfma<384, NE, true><<<NE / 32, 256, 0, stream>>>(
            xb16, erow, ecol, eab16, nullptr, eabuf, eab16,
            ew1p + (size_t)i * 384 * 256, ew2p + (size_t)i * 256 * 128,
            eb1 + (size_t)i * 256, eg1 + (size_t)i * 256, ebt1 + (size_t)i * 256,
            eb2 + (size_t)i * 128, eg2 + (size_t)i * 128, ebt2 + (size_t)i * 128);
        agg_kernel<<<(NN + 3) / 4, 256, 0, stream>>>(eabuf, starts, cnt, cinv, eidx, agg);
        mlp_mfma<256, NN, false><<<(NN + 31) / 32, 256, 0, stream>>>(
            xb16, nullptr, nullptr, nullptr, agg, xbuf, xb16,
            nw1p + (size_t)i * 256 * 256, nw2p + (size_t)i * 256 * 128,
            nb1 + (size_t)i * 256, ng1 + (size_t)i * 256, nbt1 + (size_t)i * 256,
            nb2 + (size_t)i * 128, ng2 + (size_t)i * 128, nbt2 + (size_t)i * 128);
    }
}